// Round 13
// baseline (134.138 us; speedup 1.0000x reference)
//
#include <hip/hip_runtime.h>

// Problem constants
#define N_TOTAL   65536   // B*H*W = 64*32*32
#define HW_SZ     1024    // H*W
#define CDIM      64      // embedding dim (= C)
#define K_CODES   1024
#define OUT_ELEMS 4194304 // 64*64*32*32
#define QT        256     // queries per block (32 per wave, rt=2, 8 waves)
#define NCHUNK    4       // 4 chunks of 256 codes (64 KB each), double-buffered
#define TAU       0.004f  // rescue margin (> 2x analytic bf16x3 error bound ~1.5e-3)

// ws layout (bytes):
//   0      : enorm[1024]   f32
//   4096   : hist[1024]    u32
//   8192   : partials[256] f32
//   12288  : btab (256 KB) bf16 hi/lo table in MFMA B-FRAGMENT order:
//            short index = ct*2048 + kc*1024 + h*512 + lane*8 + j
//            code = ct*16 + (lane&15), dim = (kc*4 + (lane>>4))*8 + j

typedef __attribute__((ext_vector_type(8))) short short8;
typedef __attribute__((ext_vector_type(4))) float f32x4;

__device__ __forceinline__ unsigned short f2bf(float x) {
    unsigned u = __float_as_uint(x);
    return (unsigned short)((u + 0x7FFFu + ((u >> 16) & 1u)) >> 16);   // RNE
}
__device__ __forceinline__ float bf2f(unsigned short h) {
    return __uint_as_float(((unsigned)h) << 16);
}
__device__ __forceinline__ void gload_lds16(const void* g, void* l) {
    __builtin_amdgcn_global_load_lds(
        (const __attribute__((address_space(1))) void*)g,
        (__attribute__((address_space(3))) void*)l, 16, 0, 0);
}

// ---------------------------------------------------------------- k_prep ----
__global__ void k_prep(const float* __restrict__ emb, float* __restrict__ enorm,
                       short* __restrict__ btab, unsigned int* __restrict__ hist) {
    int gid = blockIdx.x * 256 + threadIdx.x;        // 0..16383
    int r  = gid >> 4;           // code 0..1023
    int d0 = (gid & 15) * 4;     // dim base 0..60
    float4 v = *(const float4*)(emb + gid * 4);
    float s = v.x * v.x + v.y * v.y + v.z * v.z + v.w * v.w;
#pragma unroll
    for (int off = 1; off < 16; off <<= 1) s += __shfl_xor(s, off, 64);
    if ((gid & 15) == 0) enorm[r] = s;

    float vv[4] = {v.x, v.y, v.z, v.w};
    short h[4], l[4];
#pragma unroll
    for (int j = 0; j < 4; ++j) {
        unsigned short hh = f2bf(vv[j]);
        h[j] = (short)hh;
        l[j] = (short)f2bf(vv[j] - bf2f(hh));
    }
    int base = (r >> 4) * 2048 + (d0 >> 5) * 1024
             + ((((d0 >> 3) & 3) * 16 + (r & 15)) * 8) + (d0 & 7);
    *(short4*)&btab[base]       = make_short4(h[0], h[1], h[2], h[3]);
    *(short4*)&btab[base + 512] = make_short4(l[0], l[1], l[2], l[3]);

    if (gid < K_CODES) hist[gid] = 0u;
}

// -------------------------------------------------------------- k_argmin ----
// K-loop byte-identical to the proven round-5 core. Epilogue restructured for
// ZERO serialization: wave-parallel rescue (no per-flag block barriers),
// barrier-free LDS-free out-write (per-lane code preload; per-channel emb
// gather is L1-line-resident; coalesced 16B stores). Hist = global atomics
// (R12 proved them innocent), tiny k_final.
__global__ __launch_bounds__(512, 2)
void k_argmin(const float* __restrict__ x, const float* __restrict__ emb,
              const short* __restrict__ btab, const float* __restrict__ enorm,
              unsigned int* __restrict__ hist, float* __restrict__ partials,
              float* __restrict__ out) {
    __shared__ __align__(16) short bufs[2][16 * 2048];   // 2 x 64 KB chunk buffers
    __shared__ __align__(16) float ens[K_CODES];         // 4 KB exact fp32 ||e||^2
    __shared__ float xnorm[QT];
    __shared__ float rd1[QT];
    __shared__ float rd2[QT];
    __shared__ int   ri[QT];
    __shared__ int   flist[QT];
    __shared__ __align__(16) float xqfw[8][64];          // per-wave rescue x buffer
    __shared__ float spw[4];
    __shared__ int   nflag;

    const int tid  = threadIdx.x;
    const int lane = tid & 63;
    const int w    = tid >> 6;       // 0..7
    const int quad = lane >> 4;
    const int col  = lane & 15;

    const int n0  = blockIdx.x * QT;
    const int b   = n0 >> 10;
    const int hw0 = n0 & 1023;        // 256-aligned

    auto stage_async = [&](int c, int bsel) {
        const short* src = btab + c * (16 * 2048);
#pragma unroll
        for (int i = 0; i < 8; ++i) {
            int idx = i * 512 + tid;                  // 16B units, 0..4095
            gload_lds16(&src[idx * 8], (void*)&bufs[bsel][idx * 8]);
        }
    };

    stage_async(0, 0);
    if (tid < 256) gload_lds16(&enorm[tid * 4], (void*)&ens[tid * 4]);

    const float* xb = x + b * (CDIM * HW_SZ) + hw0 + col;
    short8 afr[2][2][2];     // [rt][kc][hi/lo]
#pragma unroll
    for (int rt = 0; rt < 2; ++rt) {
        float nloc = 0.f;
#pragma unroll
        for (int kc = 0; kc < 2; ++kc) {
#pragma unroll
            for (int j = 0; j < 8; ++j) {
                int c0 = (kc * 4 + quad) * 8 + j;
                float v = xb[c0 * HW_SZ + w * 32 + rt * 16];
                unsigned short hh = f2bf(v);
                afr[rt][kc][0][j] = (short)hh;
                afr[rt][kc][1][j] = (short)f2bf(v - bf2f(hh));
                nloc = __builtin_fmaf(v, v, nloc);
            }
        }
        nloc += __shfl_xor(nloc, 16, 64);
        nloc += __shfl_xor(nloc, 32, 64);
        if (quad == 0) xnorm[w * 32 + rt * 16 + col] = nloc;
    }

    float d1[8], d2[8];
    int   i1[8];
#pragma unroll
    for (int t = 0; t < 8; ++t) { d1[t] = 3.4e38f; d2[t] = 3.4e38f; i1[t] = 0; }

    __syncthreads();   // chunk 0 + ens + xnorm ready

    for (int c = 0; c < NCHUNK; ++c) {
        if (c + 1 < NCHUNK) stage_async(c + 1, (c + 1) & 1);
        const short* bs = &bufs[c & 1][0];
        const int cbase = c * 256;

        short8 Ba[4], Bb[4];          // [kc0hi, kc0lo, kc1hi, kc1lo]
        float  ena, enb;
        auto LDB = [&](short8 (&B)[4], float& en, int ctl) {
            const short* fp = bs + ctl * 2048 + lane * 8;
            B[0] = *(const short8*)(fp);
            B[1] = *(const short8*)(fp + 512);
            B[2] = *(const short8*)(fp + 1024);
            B[3] = *(const short8*)(fp + 1536);
            en   = ens[cbase + ctl * 16 + col];
        };
        auto COMP = [&](const short8 (&B)[4], float en, int mycode) {
#pragma unroll
            for (int rt = 0; rt < 2; ++rt) {
                f32x4 a0 = {0.f, 0.f, 0.f, 0.f};
                f32x4 a1 = {0.f, 0.f, 0.f, 0.f};
                a0 = __builtin_amdgcn_mfma_f32_16x16x32_bf16(afr[rt][0][1], B[0], a0, 0, 0, 0);
                a1 = __builtin_amdgcn_mfma_f32_16x16x32_bf16(afr[rt][1][1], B[2], a1, 0, 0, 0);
                a0 = __builtin_amdgcn_mfma_f32_16x16x32_bf16(afr[rt][0][0], B[1], a0, 0, 0, 0);
                a1 = __builtin_amdgcn_mfma_f32_16x16x32_bf16(afr[rt][1][0], B[3], a1, 0, 0, 0);
                a0 = __builtin_amdgcn_mfma_f32_16x16x32_bf16(afr[rt][0][0], B[0], a0, 0, 0, 0);
                a1 = __builtin_amdgcn_mfma_f32_16x16x32_bf16(afr[rt][1][0], B[2], a1, 0, 0, 0);
#pragma unroll
                for (int reg = 0; reg < 4; ++reg) {
                    int t = rt * 4 + reg;
                    float dot = a0[reg] + a1[reg];
                    float d   = __builtin_fmaf(dot, -2.f, en);
                    float d1o = d1[t];
                    d2[t] = __builtin_amdgcn_fmed3f(d, d1o, d2[t]);
                    d1[t] = fminf(d, d1o);
                    i1[t] = (d < d1o) ? mycode : i1[t];
                }
            }
        };

        LDB(Ba, ena, 0);
#pragma unroll
        for (int ctl = 0; ctl < 16; ctl += 2) {
            LDB(Bb, enb, ctl + 1);
            COMP(Ba, ena, cbase + ctl * 16 + col);
            if (ctl + 2 < 16) LDB(Ba, ena, ctl + 2);
            COMP(Bb, enb, cbase + (ctl + 1) * 16 + col);
        }
        __syncthreads();
    }

    // reduce across 16 cols per query row (codes ascend with col: lex-min ok)
#pragma unroll
    for (int t = 0; t < 8; ++t) {
        float a1 = d1[t], a2 = d2[t];
        int ai = i1[t];
#pragma unroll
        for (int off = 1; off < 16; off <<= 1) {
            float o1 = __shfl_xor(a1, off, 64);
            float o2 = __shfl_xor(a2, off, 64);
            int   oi = __shfl_xor(ai, off, 64);
            if (o1 < a1 || (o1 == a1 && oi < ai)) {
                float loser = a1; a2 = fminf(fminf(a2, o2), loser); a1 = o1; ai = oi;
            } else {
                a2 = fminf(fminf(a2, o2), o1);
            }
        }
        d1[t] = a1; d2[t] = a2; i1[t] = ai;
    }

    if (tid == 0) nflag = 0;
    if (col == 0) {
#pragma unroll
        for (int rt = 0; rt < 2; ++rt)
#pragma unroll
            for (int reg = 0; reg < 4; ++reg) {
                int t = rt * 4 + reg;
                int m = w * 32 + rt * 16 + quad * 4 + reg;
                rd1[m] = d1[t];
                rd2[m] = d2[t];
                ri [m] = i1[t];
            }
    }
    __syncthreads();

    // flag queries with margin < TAU for exact re-solve
    if (tid < QT) {
        if (rd2[tid] - rd1[tid] < TAU) {
            int slot = atomicAdd(&nflag, 1);
            flist[slot] = tid;
        }
    }
    __syncthreads();

    // ---- WAVE-PARALLEL exact fp32 rescue: wave w takes flags w, w+8, ... ----
    // No block barriers inside; same-wave LDS write->read ordered by lgkmcnt.
    for (int f = w; f < nflag; f += 8) {
        const int q = flist[f];
        xqfw[w][lane] = x[b * (CDIM * HW_SZ) + lane * HW_SZ + hw0 + q];
        float dm = 3.4e38f; int im = 0;
        for (int cd = 0; cd < 16; ++cd) {
            const int k = cd * 64 + lane;            // k ascends with cd per lane
            const float4* er = (const float4*)(emb + k * CDIM);
            float dot = 0.f;
#pragma unroll
            for (int c4 = 0; c4 < 16; ++c4) {
                float4 e  = er[c4];
                float4 xv = *(const float4*)&xqfw[w][c4 * 4];
                dot += e.x * xv.x + e.y * xv.y + e.z * xv.z + e.w * xv.w;
            }
            float d = ens[k] - 2.f * dot;            // exact fp32
            if (d < dm) { dm = d; im = k; }
        }
#pragma unroll
        for (int off = 1; off < 64; off <<= 1) {
            float od = __shfl_xor(dm, off, 64);
            int   oi = __shfl_xor(im, off, 64);
            if (od < dm || (od == dm && oi < im)) { dm = od; im = oi; }
        }
        if (lane == 0) { rd1[q] = dm; ri[q] = im; }  // distinct q per wave: no race
    }
    __syncthreads();   // all rescues visible

    // ---- hist atomics + SSE partial on FINAL indices ----
    if (tid < QT) {
        int ai = ri[tid];
        atomicAdd(&hist[ai], 1u);
        float sp = rd1[tid] + xnorm[tid];            // ||q-x||^2 (exact for rescued)
#pragma unroll
        for (int off = 32; off; off >>= 1) sp += __shfl_down(sp, off, 64);
        if (lane == 0) spw[tid >> 6] = sp;
    }
    __syncthreads();
    if (tid == 0) partials[blockIdx.x] = spw[0] + spw[1] + spw[2] + spw[3];

    // ---- barrier-free, LDS-free output write ----
    // Lane preloads its 4 codes; wave w writes channels w*8..w*8+7. Per code,
    // all 8 channels live in ONE 64B emb line -> L1-resident after first use.
    {
        const int q0 = lane * 4;
        const int c0 = ri[q0], c1 = ri[q0 + 1], c2 = ri[q0 + 2], c3 = ri[q0 + 3];
        float* ob = out + b * (CDIM * HW_SZ) + hw0 + q0;
#pragma unroll
        for (int cc = 0; cc < 8; ++cc) {
            const int c = w * 8 + cc;
            float4 v;
            v.x = emb[c0 * CDIM + c];
            v.y = emb[c1 * CDIM + c];
            v.z = emb[c2 * CDIM + c];
            v.w = emb[c3 * CDIM + c];
            *(float4*)&ob[c * HW_SZ] = v;            // coalesced 1KB per wave-instr
        }
    }
}

// --------------------------------------------------------------- k_final ----
// 1 block x 256 thr; reads partials (256) + hist (1024). Tiny.
__global__ void k_final(const float* __restrict__ partials,
                        const unsigned int* __restrict__ hist,
                        float* __restrict__ out) {
    int tid = threadIdx.x;   // 256
    float ss = partials[tid];
    float s = 0.f;
#pragma unroll
    for (int i = 0; i < 4; ++i) {
        float p = (float)hist[i * 256 + tid] * (1.0f / 65536.0f);
        s += p * logf(p + 1e-10f);
    }
    __shared__ float fin[8];
#pragma unroll
    for (int off = 32; off; off >>= 1) {
        ss += __shfl_down(ss, off, 64);
        s  += __shfl_down(s, off, 64);
    }
    if ((tid & 63) == 0) { fin[tid >> 6] = ss; fin[4 + (tid >> 6)] = s; }
    __syncthreads();
    if (tid == 0) {
        float sse = fin[0] + fin[1] + fin[2] + fin[3];
        float ent = fin[4] + fin[5] + fin[6] + fin[7];
        out[OUT_ELEMS]     = 1.25f * sse * (1.0f / (float)OUT_ELEMS);  // loss
        out[OUT_ELEMS + 1] = expf(-ent);                                // perplexity
    }
}

// ---------------------------------------------------------------- launch ----
extern "C" void kernel_launch(void* const* d_in, const int* in_sizes, int n_in,
                              void* d_out, int out_size, void* d_ws, size_t ws_size,
                              hipStream_t stream) {
    const float* x   = (const float*)d_in[0];
    const float* emb = (const float*)d_in[1];
    float* out = (float*)d_out;
    char* ws = (char*)d_ws;
    float*        enorm    = (float*)(ws);
    unsigned int* hist     = (unsigned int*)(ws + 4096);
    float*        partials = (float*)(ws + 8192);
    short*        btab     = (short*)(ws + 12288);

    k_prep  <<<64, 256, 0, stream>>>(emb, enorm, btab, hist);
    k_argmin<<<N_TOTAL / QT, 512, 0, stream>>>(x, emb, btab, enorm, hist, partials, out);
    k_final <<<1, 256, 0, stream>>>(partials, hist, out);
}